// Round 1
// 815.020 us; speedup vs baseline: 3.1101x; 3.1101x over previous
//
#include <hip/hip_runtime.h>
#include <hip/hip_bf16.h>

typedef __bf16 bf16x8 __attribute__((ext_vector_type(8)));
typedef float f32x4 __attribute__((ext_vector_type(4)));
typedef short short8 __attribute__((ext_vector_type(8)));
typedef short short4v __attribute__((ext_vector_type(4)));

// ---------------- LDS layout (units: shorts) ----------------
//   x_s / o_s : 64 x 264          @ 0       (16896 shorts)
//   scr       : 8 waves x 2304    @ 16896   (18432 shorts)
// total 35328 shorts = 70656 B  -> 2 blocks/CU (was 122880 B -> 1 block/CU)
#define XSTRIDE 264
#define SCRSZ   2304
#define QKSTR   36      // Q/K bounce: [64 tokens][36]
#define VSTR    72      // V bounce:   [32 ch][72]
#define PSTR    72      // P:          [16 tq][72]

// ---------------- workspace layout (bytes) ----------------
// flags @0 (28B), then 256-aligned regions:
#define WS_QW   256u                       // bf16 qkv_w [768][256]  (393216)
#define WS_PW   393472u                    // bf16 proj_w [256][256] (131072)
#define WS_QB   524544u                    // f32 qkv_b [768]        (3072)
#define WS_PB   527616u                    // f32 proj_b [256]       (1024)
#define WS_CMB  528640u                    // f32 cmb [64][8][64][64] (8388608)
#define WS_FULL (528640u + 8388608u)

__device__ __forceinline__ float b2f(short s) {
  unsigned u = ((unsigned)(unsigned short)s) << 16;
  float f; __builtin_memcpy(&f, &u, 4); return f;
}
__device__ __forceinline__ short f2b(float f) {
  unsigned u; __builtin_memcpy(&u, &f, 4);
  u += 0x7FFFu + ((u >> 16) & 1u);
  return (short)(u >> 16);
}
__device__ __forceinline__ bf16x8 ld8(const short* p) {
  short8 s = *(const short8*)p;
  bf16x8 f; __builtin_memcpy(&f, &s, 16); return f;
}
__device__ __forceinline__ float ldE(const void* p, size_t i, int f32) {
  return f32 ? ((const float*)p)[i] : b2f(((const short*)p)[i]);
}
__device__ __forceinline__ f32x4 mfma16(bf16x8 a, bf16x8 b, f32x4 c) {
  return __builtin_amdgcn_mfma_f32_16x16x32_bf16(a, b, c, 0, 0, 0);
}
// wait for all LDS ops, and pin ordering (rule: sched_barrier after asm waitcnt)
__device__ __forceinline__ void lgkm0() {
  asm volatile("s_waitcnt lgkmcnt(0)" ::: "memory");
  __builtin_amdgcn_sched_barrier(0);
}

// ---- dtype detector (unchanged): block b scans input b's even-index shorts.
__global__ __launch_bounds__(256) void detect_k(
    const short* p0, int n0, const short* p1, int n1, const short* p2, int n2,
    const short* p3, int n3, const short* p4, int n4, const short* p5, int n5,
    const short* p6, int n6, int* flags)
{
  const short* ps[7] = {p0, p1, p2, p3, p4, p5, p6};
  int ns[7] = {n0, n1, n2, n3, n4, n5, n6};
  int b = blockIdx.x;
  const short* p = ps[b];
  int n = ns[b];
  __shared__ int mx;
  if (threadIdx.x == 0) mx = 0;
  __syncthreads();
  int K = n >> 1; if (K > 4096) K = 4096;
  int lm = 0;
  for (int k = threadIdx.x; k < K; k += 256) {
    int e = (((int)(unsigned short)p[2 * k]) >> 7) & 0xFF;
    lm = lm > e ? lm : e;
  }
  atomicMax(&mx, lm);
  __syncthreads();
  if (threadIdx.x == 0) flags[b] = (mx >= 160) ? 1 : 0;
}

// ---- one-time prep: bf16 weights, f32 biases, combined mask+rel_bias table
__global__ __launch_bounds__(256) void prep_k(
    const void* __restrict__ qkvw, const void* __restrict__ qkvb,
    const void* __restrict__ projw, const void* __restrict__ projb,
    const void* __restrict__ btab, const void* __restrict__ maskg,
    char* __restrict__ ws, const int* __restrict__ flags, int use_cmb)
{
  const int fm = flags[1], fqw = flags[2], fqb = flags[3];
  const int fpw = flags[4], fpb = flags[5], fbt = flags[6];
  short* qw = (short*)(ws + WS_QW);
  short* pw = (short*)(ws + WS_PW);
  float* qb = (float*)(ws + WS_QB);
  float* pb = (float*)(ws + WS_PB);
  float* cmb = (float*)(ws + WS_CMB);
  const int blk = blockIdx.x, tid = threadIdx.x;
  if (blk < 512) {
    if (!use_cmb) return;
    int widx = blk >> 3, h = blk & 7;
    for (int i = tid; i < 4096; i += 256) {
      int tq = i >> 6, tk = i & 63;
      float v = -1e30f;
      if (tq < 49 && tk < 49) {
        int qr = tq / 7, qc = tq - qr * 7;
        int kr = tk / 7, kc = tk - kr * 7;
        int idx = (qr - kr + 6) * 13 + (qc - kc + 6);
        v = ldE(maskg, (size_t)widx * 2401 + tq * 49 + tk, fm)
          + ldE(btab, (size_t)idx * 8 + h, fbt);
      }
      cmb[(size_t)blk * 4096 + i] = v;
    }
  } else if (blk < 528) {
    int base = (blk - 512) * 12288;
    for (int i = tid; i < 12288; i += 256)
      qw[base + i] = f2b(ldE(qkvw, base + i, fqw));
  } else if (blk < 530) {
    int base = (blk - 528) * 32768;
    for (int i = tid; i < 32768; i += 256)
      pw[base + i] = f2b(ldE(projw, base + i, fpw));
  } else {
    for (int i = tid; i < 768; i += 256) qb[i] = ldE(qkvb, i, fqb);
    if (tid < 256) pb[tid] = ldE(projb, tid, fpb);
  }
}

template<int USE_CMB>
__global__ __launch_bounds__(512, 4) void wmsa(
    const void* __restrict__ xg, const void* __restrict__ maskg,
    const void* __restrict__ btab, const char* __restrict__ ws,
    void* __restrict__ outg, const int* __restrict__ flags)
{
  __shared__ __align__(16) short lds[35328];
  const int tid  = threadIdx.x;
  const int w    = tid >> 6;
  const int lane = tid & 63;
  const int L    = lane & 15;
  const int quad = lane >> 4;
  const int b    = blockIdx.x;

  const int fx = flags[0];
  const int fm = flags[1], fbt = flags[6];

  const short* qw  = (const short*)(ws + WS_QW);
  const short* pw  = (const short*)(ws + WS_PW);
  const float* qb  = (const float*)(ws + WS_QB);
  const float* pb  = (const float*)(ws + WS_PB);
  const float* cmb = (const float*)(ws + WS_CMB);

  short* x_s = lds;                       // reused as o_s after barrier 2
  short* scr = lds + 16896 + w * SCRSZ;   // per-wave private scratch

  // ---------------- phase 0: stage x -> LDS bf16, zero pad rows 49..63
  if (fx) {
    const float* xb = (const float*)xg + (size_t)b * (49 * 256);
    for (int i = tid; i < 1568; i += 512) {
      int t = i >> 5, c8 = i & 31;
      const float* s = xb + t * 256 + c8 * 8;
      f32x4 a = *(const f32x4*)s;
      f32x4 c = *(const f32x4*)(s + 4);
      short8 v;
      v[0] = f2b(a[0]); v[1] = f2b(a[1]); v[2] = f2b(a[2]); v[3] = f2b(a[3]);
      v[4] = f2b(c[0]); v[5] = f2b(c[1]); v[6] = f2b(c[2]); v[7] = f2b(c[3]);
      *(short8*)(x_s + t * XSTRIDE + c8 * 8) = v;
    }
  } else {
    const short* xb = (const short*)xg + (size_t)b * (49 * 256);
    for (int i = tid; i < 1568; i += 512) {
      int t = i >> 5, c8 = i & 31;
      *(short8*)(x_s + t * XSTRIDE + c8 * 8) = *(const short8*)(xb + t * 256 + c8 * 8);
    }
  }
  for (int i = tid; i < 495; i += 512) {
    int t = 49 + i / 33, c8 = i - (i / 33) * 33;
    *(short8*)(x_s + t * XSTRIDE + c8 * 8) = short8{0,0,0,0,0,0,0,0};
  }
  __syncthreads();  // barrier 1: x staged

  // ---------------- phase 1 (per wave = head h): Q,K,V into registers
  const int h = w;
  const float scale = 0.17677669529663687f;  // 32^-0.5
  bf16x8 fq[4], fk[4], fv[2][2];

  // ---- Q (scaled): weight rows h*32 .. h*32+31
  #pragma unroll
  for (int nbo = 0; nbo < 2; nbo++) {
    const int baserow = h * 32 + nbo * 16;
    const short* wr = qw + (size_t)(baserow + L) * 256 + quad * 8;
    bf16x8 wf[8];
    #pragma unroll
    for (int ks = 0; ks < 8; ks++) wf[ks] = ld8(wr + ks * 32);
    const float bias = qb[baserow + L];
    #pragma unroll
    for (int m = 0; m < 4; m++) {
      const short* ar = x_s + (m * 16 + L) * XSTRIDE + quad * 8;
      f32x4 acc = {0.f, 0.f, 0.f, 0.f};
      #pragma unroll
      for (int ks = 0; ks < 8; ks++) acc = mfma16(ld8(ar + ks * 32), wf[ks], acc);
      #pragma unroll
      for (int r = 0; r < 4; r++)
        scr[(m * 16 + quad * 4 + r) * QKSTR + nbo * 16 + L] =
            f2b((acc[r] + bias) * scale);
    }
  }
  lgkm0();
  #pragma unroll
  for (int nbq = 0; nbq < 4; nbq++)
    fq[nbq] = ld8(scr + (nbq * 16 + L) * QKSTR + quad * 8);
  lgkm0();  // fq reads done before K overwrites scratch

  // ---- K: weight rows 256 + h*32 ..
  #pragma unroll
  for (int nbo = 0; nbo < 2; nbo++) {
    const int baserow = 256 + h * 32 + nbo * 16;
    const short* wr = qw + (size_t)(baserow + L) * 256 + quad * 8;
    bf16x8 wf[8];
    #pragma unroll
    for (int ks = 0; ks < 8; ks++) wf[ks] = ld8(wr + ks * 32);
    const float bias = qb[baserow + L];
    #pragma unroll
    for (int m = 0; m < 4; m++) {
      const short* ar = x_s + (m * 16 + L) * XSTRIDE + quad * 8;
      f32x4 acc = {0.f, 0.f, 0.f, 0.f};
      #pragma unroll
      for (int ks = 0; ks < 8; ks++) acc = mfma16(ld8(ar + ks * 32), wf[ks], acc);
      #pragma unroll
      for (int r = 0; r < 4; r++)
        scr[(m * 16 + quad * 4 + r) * QKSTR + nbo * 16 + L] = f2b(acc[r] + bias);
    }
  }
  lgkm0();
  #pragma unroll
  for (int m = 0; m < 4; m++)
    fk[m] = ld8(scr + (m * 16 + L) * QKSTR + quad * 8);
  lgkm0();  // fk reads done before V overwrites scratch

  // ---- V: weight rows 512 + h*32 .. ; bounce TRANSPOSED [ch][token]
  #pragma unroll
  for (int nbo = 0; nbo < 2; nbo++) {
    const int baserow = 512 + h * 32 + nbo * 16;
    const short* wr = qw + (size_t)(baserow + L) * 256 + quad * 8;
    bf16x8 wf[8];
    #pragma unroll
    for (int ks = 0; ks < 8; ks++) wf[ks] = ld8(wr + ks * 32);
    const float bias = qb[baserow + L];
    #pragma unroll
    for (int m = 0; m < 4; m++) {
      const short* ar = x_s + (m * 16 + L) * XSTRIDE + quad * 8;
      f32x4 acc = {0.f, 0.f, 0.f, 0.f};
      #pragma unroll
      for (int ks = 0; ks < 8; ks++) acc = mfma16(ld8(ar + ks * 32), wf[ks], acc);
      short4v pk;
      #pragma unroll
      for (int r = 0; r < 4; r++) pk[r] = f2b(acc[r] + bias);
      *(short4v*)(scr + (nbo * 16 + L) * VSTR + m * 16 + quad * 4) = pk;
    }
  }
  lgkm0();
  #pragma unroll
  for (int ks2 = 0; ks2 < 2; ks2++)
    #pragma unroll
    for (int blk2 = 0; blk2 < 2; blk2++)
      fv[ks2][blk2] = ld8(scr + (blk2 * 16 + L) * VSTR + ks2 * 32 + quad * 8);
  lgkm0();  // fv reads done before P overwrites scratch

  // ---------------- phase 2+3: attention (S^T trick), all operands in regs
  const int widx = b & 63;
  const float* cmbh = cmb + ((size_t)(widx * 8 + h)) * 4096;  // [64][64]
  float oacc[4][2][4];
  #pragma unroll
  for (int nbq = 0; nbq < 4; nbq++) {
    const int tq = nbq * 16 + L;
    f32x4 s[4];
    #pragma unroll
    for (int m = 0; m < 4; m++) {
      f32x4 z = {0.f, 0.f, 0.f, 0.f};
      s[m] = mfma16(fk[m], fq[nbq], z);    // S^T tile: rows tk, cols tq
    }
    float vals[16];
    float mx = -1e30f;
    if (USE_CMB) {
      #pragma unroll
      for (int m = 0; m < 4; m++) {
        f32x4 c4 = *(const f32x4*)(cmbh + tq * 64 + m * 16 + quad * 4);
        #pragma unroll
        for (int r = 0; r < 4; r++) {
          float v = s[m][r] + c4[r];
          vals[m * 4 + r] = v;
          mx = fmaxf(mx, v);
        }
      }
    } else {
      const int tqc = tq < 49 ? tq : 48;
      const int qr = tqc / 7, qc = tqc - qr * 7;
      #pragma unroll
      for (int m = 0; m < 4; m++) {
        #pragma unroll
        for (int r = 0; r < 4; r++) {
          const int tk = m * 16 + quad * 4 + r;
          float v = -1e30f;
          if (tk < 49) {
            const int kr = tk / 7, kc = tk - kr * 7;
            const int idx = (qr - kr + 6) * 13 + (qc - kc + 6);
            v = s[m][r] + ldE(btab, (size_t)idx * 8 + h, fbt)
                        + ldE(maskg, (size_t)widx * 2401 + tqc * 49 + tk, fm);
          }
          vals[m * 4 + r] = v;
          mx = fmaxf(mx, v);
        }
      }
    }
    mx = fmaxf(mx, __shfl_xor(mx, 16));
    mx = fmaxf(mx, __shfl_xor(mx, 32));
    float sum = 0.f;
    #pragma unroll
    for (int i2 = 0; i2 < 16; i2++) { vals[i2] = __expf(vals[i2] - mx); sum += vals[i2]; }
    sum += __shfl_xor(sum, 16);
    sum += __shfl_xor(sum, 32);
    const float inv = 1.f / sum;
    #pragma unroll
    for (int m = 0; m < 4; m++) {             // P -> bf16, C-layout -> A-layout
      short4v pk;
      #pragma unroll
      for (int r = 0; r < 4; r++) pk[r] = f2b(vals[m * 4 + r] * inv);
      *(short4v*)(scr + L * PSTR + m * 16 + quad * 4) = pk;
    }
    lgkm0();  // P writes visible before reads
    f32x4 o0 = {0.f,0.f,0.f,0.f}, o1 = {0.f,0.f,0.f,0.f};
    #pragma unroll
    for (int ks2 = 0; ks2 < 2; ks2++) {
      bf16x8 fp = ld8(scr + L * PSTR + ks2 * 32 + quad * 8);
      o0 = mfma16(fp, fv[ks2][0], o0);
      o1 = mfma16(fp, fv[ks2][1], o1);
    }
    lgkm0();  // P reads done before next nbq overwrites
    #pragma unroll
    for (int r = 0; r < 4; r++) { oacc[nbq][0][r] = o0[r]; oacc[nbq][1][r] = o1[r]; }
  }

  __syncthreads();  // barrier 2: all waves past x_s reads -> overlay with o
  short* o_s = lds;
  #pragma unroll
  for (int nbq = 0; nbq < 4; nbq++)
    #pragma unroll
    for (int nbd = 0; nbd < 2; nbd++)
      #pragma unroll
      for (int r = 0; r < 4; r++)
        o_s[(nbq * 16 + quad * 4 + r) * XSTRIDE + h * 32 + nbd * 16 + L] =
            f2b(oacc[nbq][nbd][r]);
  __syncthreads();  // barrier 3: o_s complete

  // ---------------- phase 4: out = o @ proj_w^T + proj_b (bf16 weights)
  {
    const int mb = w & 3, half = w >> 2;
    bf16x8 ao[8];
    const short* orow = o_s + (mb * 16 + L) * XSTRIDE + quad * 8;
    #pragma unroll
    for (int ks = 0; ks < 8; ks++) ao[ks] = ld8(orow + ks * 32);
    for (int i = 0; i < 8; i++) {
      const int nb = half * 8 + i;
      const short* wr = pw + (size_t)(nb * 16 + L) * 256 + quad * 8;
      bf16x8 wf[8];
      #pragma unroll
      for (int ks = 0; ks < 8; ks++) wf[ks] = ld8(wr + ks * 32);
      f32x4 acc = {0.f, 0.f, 0.f, 0.f};
      #pragma unroll
      for (int ks = 0; ks < 8; ks++) acc = mfma16(ao[ks], wf[ks], acc);
      const float bias = pb[nb * 16 + L];
      #pragma unroll
      for (int r = 0; r < 4; r++) {
        const int t = mb * 16 + quad * 4 + r;
        if (t < 49) {
          size_t ofs = (size_t)b * (49 * 256) + (size_t)t * 256 + nb * 16 + L;
          float val = acc[r] + bias;
          if (fx) ((float*)outg)[ofs] = val;
          else    ((short*)outg)[ofs] = f2b(val);
        }
      }
    }
  }
}

extern "C" void kernel_launch(void* const* d_in, const int* in_sizes, int n_in,
                              void* d_out, int out_size, void* d_ws, size_t ws_size,
                              hipStream_t stream) {
  (void)n_in; (void)out_size;
  int B = in_sizes[0] / (49 * 256);  // 4096
  char* ws = (char*)d_ws;
  int* flags = (int*)ws;
  detect_k<<<7, 256, 0, stream>>>(
      (const short*)d_in[0], in_sizes[0], (const short*)d_in[1], in_sizes[1],
      (const short*)d_in[2], in_sizes[2], (const short*)d_in[3], in_sizes[3],
      (const short*)d_in[4], in_sizes[4], (const short*)d_in[5], in_sizes[5],
      (const short*)d_in[6], in_sizes[6], flags);
  const int use_cmb = ws_size >= (size_t)WS_FULL;
  prep_k<<<531, 256, 0, stream>>>(d_in[2], d_in[3], d_in[4], d_in[5], d_in[6],
                                  d_in[1], ws, flags, use_cmb);
  if (use_cmb)
    wmsa<1><<<B, 512, 0, stream>>>(d_in[0], d_in[1], d_in[6], ws, d_out, flags);
  else
    wmsa<0><<<B, 512, 0, stream>>>(d_in[0], d_in[1], d_in[6], ws, d_out, flags);
}